// Round 1
// 177.671 us; speedup vs baseline: 1.0200x; 1.0200x over previous
//
#include <hip/hip_runtime.h>
#include <stdint.h>

// LinearAttention fused: qkv GEMM + dual softmax + linear attention + Wout GEMM + LayerNorm2d
// Shapes: b=32, c=128, n=64*64=4096, heads=4, dim_head=32.
// All GEMMs via v_mfma_f32_16x16x32_bf16 (fp32 accum).
//
// R2: atomic-free (R1 k1 spun ~395us in fp32 atomicAdd CAS loops).
// R3: __launch_bounds__(512,4) capped VGPR at 64 -> scratch spill storm.
// R4: spill reduced but VGPR pinned at 128-cap; k1 ~invariant => wq refetch dominated.
// R5: k1 rebuilt: 1024-thr blocks, 16 waves, wq frags persistent in VGPRs. 181us total.
// R6: k3 was the largest kernel (51us) with ALL pipes <25% (MfmaUtil 3.5, VALU 12.7,
//     HBM 21%) => latency-bound on its 2-phase (out2-LDS-barrier-Wout) chain, 3.4x off
//     its 15us BW floor. Algebraic fold: y = Wout @ concat_h(ctx_h @ q_h)
//     = (Wout @ blockdiag_h(ctxN)) @ qsm = Wbig[b] @ qsm. Wbig (128x128/batch, 64 MFMAs)
//     is computed in k2; k3 becomes a single-phase K=128 GEMM + LN: no LDS, no barrier,
//     36 independent 16B loads, 32 MFMAs. ctxn buffer removed.

constexpr int B_   = 32;
constexpr int C_   = 128;
constexpr int N_   = 4096;
constexpr int O3_  = 384;   // 3*128 qkv rows
constexpr int NSUB = 8;     // 64-wide n-subtiles per k1 block
constexpr int TPB_ = 8;     // k1 blocks per batch (4096 / 512)

using short8  = __attribute__((ext_vector_type(8))) short;
using short4v = __attribute__((ext_vector_type(4))) short;
using float4v = __attribute__((ext_vector_type(4))) float;

__device__ __forceinline__ unsigned short bf16_rne(float f) {
    union { float f; uint32_t u; } v; v.f = f;
    uint32_t u = v.u;
    u += 0x7FFFu + ((u >> 16) & 1u);   // round-to-nearest-even
    return (unsigned short)(u >> 16);
}
__device__ __forceinline__ float bf2f(unsigned short h) {
    union { uint32_t u; float f; } v; v.u = ((uint32_t)h) << 16; return v.f;
}

// workspace layout (bytes)
constexpr size_t OFF_WQ   = 0;          // Wqkv bf16: 384*128*2 = 98304
constexpr size_t OFF_WO   = 98304;      // Wout bf16: 128*128*2 = 32768 -> 131072
constexpr size_t OFF_SP   = 131072;     // S partials [b][8][128] f32: 131072 -> 262144
constexpr size_t OFF_CTXP = 262144;     // ctx partials [b][8][4096] f32: 4194304 -> 4456448
constexpr size_t OFF_WBIG = 4456448;    // Wbig bf16 [b][o][h*32+d]: 32*128*128*2 = 1048576 -> 5505024
constexpr size_t OFF_QSM  = 5505024;    // q-softmax bf16 [b][n][h*32+d]: 33554432 -> 39059456
// total 39,059,456 bytes

__global__ __launch_bounds__(256) void k0_prep(const float* __restrict__ Wqkv,
                                               const float* __restrict__ Wout,
                                               unsigned short* __restrict__ wq,
                                               unsigned short* __restrict__ wo) {
    int t = blockIdx.x * 256 + threadIdx.x;      // grid = 192*256 = 49152
    if (t < O3_ * C_) wq[t] = bf16_rne(Wqkv[t]);
    if (t < C_ * C_)  wo[t] = bf16_rne(Wout[t]);
}

// K1: per (b, 512-wide n-tile): 16 waves. Waves 0-11: gemm wave w owns qkv row-pair w
// (rows w*32..w*32+31) with wq frags persistent in registers; covers all 64 n-cols.
// Waves 12-15: stage next x subtile (fp32->bf16, double-buffered). All 16 waves then
// run one context-MFMA tile each + S partial sums. Partials to global at end.
__global__ __launch_bounds__(1024) void k1_qkv(const float* __restrict__ x,
                                               const unsigned short* __restrict__ wq,
                                               unsigned short* __restrict__ qsm,
                                               float* __restrict__ ctx_part,
                                               float* __restrict__ S_part) {
    __shared__ __align__(16) unsigned short xs0[64 * 136];   // [n][c], stride 136 (dbuf A)
    __shared__ __align__(16) unsigned short xs1[64 * 136];   // dbuf B
    __shared__ __align__(16) unsigned short ek[128 * 72];    // [h*32+d][n], stride 72
    __shared__ __align__(16) unsigned short vsh[128 * 72];   // [h*32+e][n]

    const int b    = blockIdx.y;
    const int tblk = blockIdx.x;                 // 0..7
    const int tid  = threadIdx.x;

    const int lane = tid & 63;
    const int wv   = tid >> 6;                   // 0..15
    const int l15  = lane & 15;
    const int quad = lane >> 4;

    const float4v zero = {0.f, 0.f, 0.f, 0.f};

    // --- persistent wq fragments for gemm waves (loaded ONCE per block) ---
    short8 wfa[8];                               // [half(0: rows +0..15, 1: +16..31)*4 + kk]
    if (wv < 12) {
        const unsigned short* wqp = wq + (wv * 32 + l15) * C_ + quad * 8;
        #pragma unroll
        for (int kk = 0; kk < 4; kk++) {
            wfa[kk]     = *(const short8*)(wqp + kk * 32);
            wfa[4 + kk] = *(const short8*)(wqp + 16 * C_ + kk * 32);
        }
    }

    // --- staging lanes (waves 12-15): 256 threads, each 32 c-rows of one n ---
    const int sid = tid & 255;                   // for wv>=12: 0..255
    const int snl = sid & 63;                    // n within subtile
    const int scg = sid >> 6;                    // c group of 32
    const float* xbase = x + ((size_t)b * C_ + (size_t)scg * 32) * N_ + snl;
    float xv[32];
    auto load_x = [&](int s) {
        const float* xp = xbase + (tblk * NSUB + s) * 64;
        #pragma unroll
        for (int i = 0; i < 32; i++) xv[i] = xp[(size_t)i * N_];
    };
    auto store_x = [&](unsigned short* xs) {
        unsigned short* dst = &xs[snl * 136 + scg * 32];
        #pragma unroll
        for (int ii = 0; ii < 4; ii++) {
            short8 v8;
            #pragma unroll
            for (int j = 0; j < 8; j++) v8[j] = (short)bf16_rne(xv[ii * 8 + j]);
            *(short8*)(dst + ii * 8) = v8;
        }
    };

    if (wv >= 12) { load_x(0); store_x(xs0); }
    unsigned short* xs_cur = xs0;
    unsigned short* xs_nxt = xs1;

    float4v cacc = zero;                         // this wave's single ctx tile
    float s_acc  = 0.f;
    const int ch  = wv >> 2;                     // ctx tile coords (valid for all 16 wv)
    const int cdt = (wv >> 1) & 1;
    const int cet = wv & 1;

    for (int s = 0; s < NSUB; s++) {
        const int ns = (tblk * NSUB + s) * 64;
        __syncthreads();                         // A: xs_cur staged; ek/vsh free

        if (wv < 12) {
            #pragma unroll
            for (int ct = 0; ct < 4; ct++) {
                short8 bfx[4];
                #pragma unroll
                for (int kk = 0; kk < 4; kk++)
                    bfx[kk] = *(const short8*)&xs_cur[(ct * 16 + l15) * 136 + kk * 32 + quad * 8];
                float4v acc0 = zero, acc1 = zero;
                #pragma unroll
                for (int kk = 0; kk < 4; kk++) {
                    acc0 = __builtin_amdgcn_mfma_f32_16x16x32_bf16(wfa[kk],     bfx[kk], acc0, 0, 0, 0);
                    acc1 = __builtin_amdgcn_mfma_f32_16x16x32_bf16(wfa[4 + kk], bfx[kk], acc1, 0, 0, 0);
                }
                const int ncol = ct * 16 + l15;
                // C/D layout: col = l15, row = quad*4 + r (acc0: rows 0-15, acc1: 16-31)
                if (wv < 4) {                    // q, head h = wv: softmax over d per column
                    float e0[4], e1[4], z = 0.f;
                    #pragma unroll
                    for (int r = 0; r < 4; r++) {
                        e0[r] = __expf(acc0[r]); e1[r] = __expf(acc1[r]);
                        z += e0[r] + e1[r];
                    }
                    z += __shfl_xor(z, 16, 64);
                    z += __shfl_xor(z, 32, 64);
                    const float iz = 1.0f / z;
                    unsigned short* qp = qsm + ((size_t)b * N_ + ns + ncol) * C_ + wv * 32 + quad * 4;
                    short4v s0, s1;
                    #pragma unroll
                    for (int r = 0; r < 4; r++) {
                        s0[r] = (short)bf16_rne(e0[r] * iz);
                        s1[r] = (short)bf16_rne(e1[r] * iz);
                    }
                    *(short4v*)qp = s0;          // d = quad*4..+3
                    *(short4v*)(qp + 16) = s1;   // d = 16+quad*4..+3
                } else if (wv < 8) {             // k, head h = wv-4: exp -> LDS
                    const int row0 = (wv - 4) * 32 + quad * 4;
                    #pragma unroll
                    for (int r = 0; r < 4; r++) {
                        ek[(row0 + r) * 72 + ncol]      = bf16_rne(__expf(acc0[r]));
                        ek[(row0 + 16 + r) * 72 + ncol] = bf16_rne(__expf(acc1[r]));
                    }
                } else {                         // v, head h = wv-8 -> LDS
                    const int row0 = (wv - 8) * 32 + quad * 4;
                    #pragma unroll
                    for (int r = 0; r < 4; r++) {
                        vsh[(row0 + r) * 72 + ncol]      = bf16_rne(acc0[r]);
                        vsh[(row0 + 16 + r) * 72 + ncol] = bf16_rne(acc1[r]);
                    }
                }
            }
        } else {
            if (s + 1 < NSUB) { load_x(s + 1); store_x(xs_nxt); }   // overlaps gemm phase
        }
        __syncthreads();                         // B: ek/vsh ready; xs_nxt staged

        // context: cacc[d][e] += sum_n expk[d][n] * v[e][n]  (one 16x16 tile per wave)
        {
            const unsigned short* ap = &ek[(ch * 32 + cdt * 16 + l15) * 72 + quad * 8];
            const unsigned short* bp = &vsh[(ch * 32 + cet * 16 + l15) * 72 + quad * 8];
            #pragma unroll
            for (int kk = 0; kk < 2; kk++) {
                short8 a  = *(const short8*)(ap + kk * 32);
                short8 bb = *(const short8*)(bp + kk * 32);
                cacc = __builtin_amdgcn_mfma_f32_16x16x32_bf16(a, bb, cacc, 0, 0, 0);
            }
        }
        {   // S partial sums: 1024 threads = 128 rows x 8 threads x 8 elems
            const unsigned short* ep = &ek[(tid >> 3) * 72 + (tid & 7) * 8];
            short8 e0 = *(const short8*)ep;      // one ds_read_b128
            float ss = 0.f;
            #pragma unroll
            for (int j = 0; j < 8; j++) ss += bf2f((unsigned short)e0[j]);
            s_acc += ss;
        }
        { unsigned short* t = xs_cur; xs_cur = xs_nxt; xs_nxt = t; }
    }

    // write-out: plain stores, no atomics
    {
        float* cp = ctx_part + ((size_t)(b * TPB_ + tblk) << 12)
                  + ((ch * 32 + cdt * 16 + quad * 4) * 32 + cet * 16 + l15);
        #pragma unroll
        for (int r = 0; r < 4; r++) cp[r * 32] = cacc[r];
    }
    {
        float ss = s_acc;
        ss += __shfl_xor(ss, 1, 64);
        ss += __shfl_xor(ss, 2, 64);
        ss += __shfl_xor(ss, 4, 64);
        if ((tid & 7) == 0)
            S_part[(size_t)(b * TPB_ + tblk) * 128 + (tid >> 3)] = ss;
    }
}

// K2: reduce 8 ctx partials + S, then fold the whole back-end weight:
//   Wbig[b][o][h*32+d] = sum_e Wout[o][h*32+e] * ctx[b][h][d][e] / S[b][h][d]
// One block per batch, 512 threads (8 waves). Phase 1: Sinv. Phase 2: reduce ctx,
// scale, bf16 -> LDS [hd][e] (stride 40 shorts: 16B-aligned b128 reads, 2-way banks).
// Phase 3: 64 MFMAs (wave wv owns o-tile wv, loops 8 hd-tiles, K=32 per head).
__global__ __launch_bounds__(512) void k2_reduce(const float* __restrict__ ctx_part,
                                                 const float* __restrict__ S_part,
                                                 const unsigned short* __restrict__ wo,
                                                 unsigned short* __restrict__ wbig) {
    __shared__ float Sinv[128];
    __shared__ __align__(16) unsigned short ctxb[128 * 40];  // [h*32+d][e]
    const int b   = blockIdx.x;
    const int tid = threadIdx.x;

    if (tid < 128) {
        float s = 0.f;
        #pragma unroll
        for (int t = 0; t < TPB_; t++)
            s += S_part[(size_t)(b * TPB_ + t) * 128 + tid];
        Sinv[tid] = 1.0f / s;
    }
    __syncthreads();

    #pragma unroll
    for (int i = 0; i < 8; i++) {
        const int ei = i * 512 + tid;            // flat [h][d][e]
        float v = 0.f;
        #pragma unroll
        for (int t = 0; t < TPB_; t++)
            v += ctx_part[((size_t)(b * TPB_ + t) << 12) + ei];
        ctxb[(ei >> 5) * 40 + (ei & 31)] = bf16_rne(v * Sinv[ei >> 5]);
    }
    __syncthreads();

    const int lane = tid & 63, wv = tid >> 6, l15 = lane & 15, quad = lane >> 4;
    const float4v zero = {0.f, 0.f, 0.f, 0.f};
    unsigned short* wb = wbig + (size_t)b * (C_ * C_);
    #pragma unroll
    for (int ht = 0; ht < 8; ht++) {             // hd-tile: head ht>>1, d-half ht&1
        const int h_ = ht >> 1;
        short8 a  = *(const short8*)(wo + (wv * 16 + l15) * C_ + h_ * 32 + quad * 8);
        short8 bb = *(const short8*)&ctxb[(h_ * 32 + (ht & 1) * 16 + l15) * 40 + quad * 8];
        float4v c4 = __builtin_amdgcn_mfma_f32_16x16x32_bf16(a, bb, zero, 0, 0, 0);
        // C layout: row (o within tile) = quad*4+r, col (hd within tile) = l15
        #pragma unroll
        for (int r = 0; r < 4; r++)
            wb[(wv * 16 + quad * 4 + r) * C_ + ht * 16 + l15] = bf16_rne(c4[r]);
    }
}

// K3: single-phase y = Wbig[b] @ qsm + bout, LayerNorm over c. No LDS, no barrier.
// Per block: 64 n-cols of one batch; wave wv owns n-cols wv*16..+15, all 128 o.
__global__ __launch_bounds__(256) void k3_out(const unsigned short* __restrict__ qsm,
                                              const unsigned short* __restrict__ wbig,
                                              const float* __restrict__ bout,
                                              const float* __restrict__ lnw,
                                              const float* __restrict__ lnb,
                                              float* __restrict__ out) {
    const int b   = blockIdx.y;
    const int n0  = blockIdx.x * 64;
    const int tid = threadIdx.x;

    const int lane = tid & 63, wv = tid >> 6, l15 = lane & 15, quad = lane >> 4;
    const int nl = wv * 16 + l15;
    const size_t n = (size_t)n0 + nl;

    const float4v zero = {0.f, 0.f, 0.f, 0.f};

    // B-frags: this n-column of qsm, K=128 (4 chunks of 32)
    short8 bq[4];
    #pragma unroll
    for (int kk = 0; kk < 4; kk++)
        bq[kk] = *(const short8*)(qsm + ((size_t)b * N_ + n) * C_ + kk * 32 + quad * 8);

    const unsigned short* wbp = wbig + (size_t)b * (C_ * C_);
    float4v acc[8];
    #pragma unroll
    for (int ot = 0; ot < 8; ot++) {
        const unsigned short* wp = wbp + (ot * 16 + l15) * C_ + quad * 8;
        short8 w0 = *(const short8*)(wp);
        short8 w1 = *(const short8*)(wp + 32);
        short8 w2 = *(const short8*)(wp + 64);
        short8 w3 = *(const short8*)(wp + 96);
        float4v a = zero;
        a = __builtin_amdgcn_mfma_f32_16x16x32_bf16(w0, bq[0], a, 0, 0, 0);
        a = __builtin_amdgcn_mfma_f32_16x16x32_bf16(w1, bq[1], a, 0, 0, 0);
        a = __builtin_amdgcn_mfma_f32_16x16x32_bf16(w2, bq[2], a, 0, 0, 0);
        a = __builtin_amdgcn_mfma_f32_16x16x32_bf16(w3, bq[3], a, 0, 0, 0);
        acc[ot] = a;
    }

    // bias + LayerNorm over the 128 channels of this column
    float sum = 0.f, sq = 0.f;
    #pragma unroll
    for (int ot = 0; ot < 8; ot++) {
        #pragma unroll
        for (int r = 0; r < 4; r++) {
            const int o = ot * 16 + quad * 4 + r;
            const float y = acc[ot][r] + bout[o];
            acc[ot][r] = y;
            sum += y; sq += y * y;
        }
    }
    sum += __shfl_xor(sum, 16, 64);
    sum += __shfl_xor(sum, 32, 64);
    sq  += __shfl_xor(sq, 16, 64);
    sq  += __shfl_xor(sq, 32, 64);
    const float mean = sum * (1.0f / 128.0f);
    const float var  = sq * (1.0f / 128.0f) - mean * mean;   // biased, matches jnp.var
    const float rstd = rsqrtf(var + 1e-5f);

    #pragma unroll
    for (int ot = 0; ot < 8; ot++) {
        #pragma unroll
        for (int r = 0; r < 4; r++) {
            const int o = ot * 16 + quad * 4 + r;
            out[((size_t)b * C_ + o) * N_ + n] = (acc[ot][r] - mean) * rstd * lnw[o] + lnb[o];
        }
    }
}

extern "C" void kernel_launch(void* const* d_in, const int* in_sizes, int n_in,
                              void* d_out, int out_size, void* d_ws, size_t ws_size,
                              hipStream_t stream) {
    const float* x    = (const float*)d_in[0];
    const float* Wqkv = (const float*)d_in[1];
    const float* Wout = (const float*)d_in[2];
    const float* bout = (const float*)d_in[3];
    const float* lnw  = (const float*)d_in[4];
    const float* lnb  = (const float*)d_in[5];
    float* out = (float*)d_out;

    char* ws = (char*)d_ws;
    unsigned short* wq   = (unsigned short*)(ws + OFF_WQ);
    unsigned short* wo   = (unsigned short*)(ws + OFF_WO);
    float* S_part        = (float*)(ws + OFF_SP);
    float* ctx_part      = (float*)(ws + OFF_CTXP);
    unsigned short* wbig = (unsigned short*)(ws + OFF_WBIG);
    unsigned short* qsm  = (unsigned short*)(ws + OFF_QSM);

    k0_prep<<<192, 256, 0, stream>>>(Wqkv, Wout, wq, wo);
    k1_qkv<<<dim3(TPB_, B_), 1024, 0, stream>>>(x, wq, qsm, ctx_part, S_part);
    k2_reduce<<<B_, 512, 0, stream>>>(ctx_part, S_part, wo, wbig);
    k3_out<<<dim3(N_ / 64, B_), 256, 0, stream>>>(qsm, wbig, bout, lnw, lnb, out);
}

// Round 2
// 159.923 us; speedup vs baseline: 1.1332x; 1.1110x over previous
//
#include <hip/hip_runtime.h>
#include <stdint.h>

// LinearAttention fused: qkv GEMM + dual softmax + linear attention + Wout GEMM + LayerNorm2d
// Shapes: b=32, c=128, n=64*64=4096, heads=4, dim_head=32.
// All GEMMs via v_mfma_f32_16x16x32_bf16 (fp32 accum).
//
// R5: k1 rebuilt: 1024-thr blocks, 16 waves, wq frags persistent in VGPRs. 181us total.
// R6: algebraic fold y = (Wout @ blockdiag_h(ctxN)) @ qsm = Wbig[b] @ qsm. k3 single-phase.
//     Result: k3 51->47.5us only. Counters: ALL pipes still idle (Mfma 3.2, VALU 11,
//     HBM 23%, occ 33%), VGPR=64 => per-ot {4 L2 loads -> drain -> 4 MFMA} serialization;
//     wbig re-read from L2 by every wave (256MB L2 traffic), no ILP headroom.
// R7: (a) k2 writes Wbig in FRAG-MAJOR tiled order (chunk c=ot*4+kk, lane-ordered 16B
//     frags) so k3 stages all 32KB into LDS with a linear conflict-free copy and inner
//     loop is lane-contiguous ds_read_b128 (no L2 latency in the loop). k3 blocks ->
//     512 thr / 128 n-cols (one stage serves 2x output). (b) k2 split: k2a (256 blocks)
//     reduces ctx partials -> ctxn bf16; k2b (32 blocks) folds Wout @ ctxN into tiled
//     Wbig. R6's k2 ran 32 blocks on 256 CUs.

constexpr int B_   = 32;
constexpr int C_   = 128;
constexpr int N_   = 4096;
constexpr int O3_  = 384;   // 3*128 qkv rows
constexpr int NSUB = 8;     // 64-wide n-subtiles per k1 block
constexpr int TPB_ = 8;     // k1 blocks per batch (4096 / 512)

using short8  = __attribute__((ext_vector_type(8))) short;
using short4v = __attribute__((ext_vector_type(4))) short;
using float4v = __attribute__((ext_vector_type(4))) float;

__device__ __forceinline__ unsigned short bf16_rne(float f) {
    union { float f; uint32_t u; } v; v.f = f;
    uint32_t u = v.u;
    u += 0x7FFFu + ((u >> 16) & 1u);   // round-to-nearest-even
    return (unsigned short)(u >> 16);
}
__device__ __forceinline__ float bf2f(unsigned short h) {
    union { uint32_t u; float f; } v; v.u = ((uint32_t)h) << 16; return v.f;
}

// workspace layout (bytes)
constexpr size_t OFF_WQ   = 0;          // Wqkv bf16: 384*128*2 = 98304
constexpr size_t OFF_WO   = 98304;      // Wout bf16: 128*128*2 = 32768 -> 131072
constexpr size_t OFF_SP   = 131072;     // S partials [b][8][128] f32: 131072 -> 262144
constexpr size_t OFF_CTXP = 262144;     // ctx partials [b][8][4096] f32: 4194304 -> 4456448
constexpr size_t OFF_CTXN = 4456448;    // ctxN bf16 [b][hd][e]: 262144 -> 4718592
constexpr size_t OFF_WBIG = 4718592;    // Wbig bf16 TILED [b][c=ot*4+kk][lane][8]: 1048576 -> 5767168
constexpr size_t OFF_QSM  = 5767168;    // q-softmax bf16 [b][n][h*32+d]: 33554432 -> 39321600
// total 39,321,600 bytes

__global__ __launch_bounds__(256) void k0_prep(const float* __restrict__ Wqkv,
                                               const float* __restrict__ Wout,
                                               unsigned short* __restrict__ wq,
                                               unsigned short* __restrict__ wo) {
    int t = blockIdx.x * 256 + threadIdx.x;      // grid = 192*256 = 49152
    if (t < O3_ * C_) wq[t] = bf16_rne(Wqkv[t]);
    if (t < C_ * C_)  wo[t] = bf16_rne(Wout[t]);
}

// K1: per (b, 512-wide n-tile): 16 waves. Waves 0-11: gemm wave w owns qkv row-pair w
// (rows w*32..w*32+31) with wq frags persistent in registers; covers all 64 n-cols.
// Waves 12-15: stage next x subtile (fp32->bf16, double-buffered). All 16 waves then
// run one context-MFMA tile each + S partial sums. Partials to global at end.
__global__ __launch_bounds__(1024) void k1_qkv(const float* __restrict__ x,
                                               const unsigned short* __restrict__ wq,
                                               unsigned short* __restrict__ qsm,
                                               float* __restrict__ ctx_part,
                                               float* __restrict__ S_part) {
    __shared__ __align__(16) unsigned short xs0[64 * 136];   // [n][c], stride 136 (dbuf A)
    __shared__ __align__(16) unsigned short xs1[64 * 136];   // dbuf B
    __shared__ __align__(16) unsigned short ek[128 * 72];    // [h*32+d][n], stride 72
    __shared__ __align__(16) unsigned short vsh[128 * 72];   // [h*32+e][n]

    const int b    = blockIdx.y;
    const int tblk = blockIdx.x;                 // 0..7
    const int tid  = threadIdx.x;

    const int lane = tid & 63;
    const int wv   = tid >> 6;                   // 0..15
    const int l15  = lane & 15;
    const int quad = lane >> 4;

    const float4v zero = {0.f, 0.f, 0.f, 0.f};

    // --- persistent wq fragments for gemm waves (loaded ONCE per block) ---
    short8 wfa[8];                               // [half(0: rows +0..15, 1: +16..31)*4 + kk]
    if (wv < 12) {
        const unsigned short* wqp = wq + (wv * 32 + l15) * C_ + quad * 8;
        #pragma unroll
        for (int kk = 0; kk < 4; kk++) {
            wfa[kk]     = *(const short8*)(wqp + kk * 32);
            wfa[4 + kk] = *(const short8*)(wqp + 16 * C_ + kk * 32);
        }
    }

    // --- staging lanes (waves 12-15): 256 threads, each 32 c-rows of one n ---
    const int sid = tid & 255;                   // for wv>=12: 0..255
    const int snl = sid & 63;                    // n within subtile
    const int scg = sid >> 6;                    // c group of 32
    const float* xbase = x + ((size_t)b * C_ + (size_t)scg * 32) * N_ + snl;
    float xv[32];
    auto load_x = [&](int s) {
        const float* xp = xbase + (tblk * NSUB + s) * 64;
        #pragma unroll
        for (int i = 0; i < 32; i++) xv[i] = xp[(size_t)i * N_];
    };
    auto store_x = [&](unsigned short* xs) {
        unsigned short* dst = &xs[snl * 136 + scg * 32];
        #pragma unroll
        for (int ii = 0; ii < 4; ii++) {
            short8 v8;
            #pragma unroll
            for (int j = 0; j < 8; j++) v8[j] = (short)bf16_rne(xv[ii * 8 + j]);
            *(short8*)(dst + ii * 8) = v8;
        }
    };

    if (wv >= 12) { load_x(0); store_x(xs0); }
    unsigned short* xs_cur = xs0;
    unsigned short* xs_nxt = xs1;

    float4v cacc = zero;                         // this wave's single ctx tile
    float s_acc  = 0.f;
    const int ch  = wv >> 2;                     // ctx tile coords (valid for all 16 wv)
    const int cdt = (wv >> 1) & 1;
    const int cet = wv & 1;

    for (int s = 0; s < NSUB; s++) {
        const int ns = (tblk * NSUB + s) * 64;
        __syncthreads();                         // A: xs_cur staged; ek/vsh free

        if (wv < 12) {
            #pragma unroll
            for (int ct = 0; ct < 4; ct++) {
                short8 bfx[4];
                #pragma unroll
                for (int kk = 0; kk < 4; kk++)
                    bfx[kk] = *(const short8*)&xs_cur[(ct * 16 + l15) * 136 + kk * 32 + quad * 8];
                float4v acc0 = zero, acc1 = zero;
                #pragma unroll
                for (int kk = 0; kk < 4; kk++) {
                    acc0 = __builtin_amdgcn_mfma_f32_16x16x32_bf16(wfa[kk],     bfx[kk], acc0, 0, 0, 0);
                    acc1 = __builtin_amdgcn_mfma_f32_16x16x32_bf16(wfa[4 + kk], bfx[kk], acc1, 0, 0, 0);
                }
                const int ncol = ct * 16 + l15;
                // C/D layout: col = l15, row = quad*4 + r (acc0: rows 0-15, acc1: 16-31)
                if (wv < 4) {                    // q, head h = wv: softmax over d per column
                    float e0[4], e1[4], z = 0.f;
                    #pragma unroll
                    for (int r = 0; r < 4; r++) {
                        e0[r] = __expf(acc0[r]); e1[r] = __expf(acc1[r]);
                        z += e0[r] + e1[r];
                    }
                    z += __shfl_xor(z, 16, 64);
                    z += __shfl_xor(z, 32, 64);
                    const float iz = 1.0f / z;
                    unsigned short* qp = qsm + ((size_t)b * N_ + ns + ncol) * C_ + wv * 32 + quad * 4;
                    short4v s0, s1;
                    #pragma unroll
                    for (int r = 0; r < 4; r++) {
                        s0[r] = (short)bf16_rne(e0[r] * iz);
                        s1[r] = (short)bf16_rne(e1[r] * iz);
                    }
                    *(short4v*)qp = s0;          // d = quad*4..+3
                    *(short4v*)(qp + 16) = s1;   // d = 16+quad*4..+3
                } else if (wv < 8) {             // k, head h = wv-4: exp -> LDS
                    const int row0 = (wv - 4) * 32 + quad * 4;
                    #pragma unroll
                    for (int r = 0; r < 4; r++) {
                        ek[(row0 + r) * 72 + ncol]      = bf16_rne(__expf(acc0[r]));
                        ek[(row0 + 16 + r) * 72 + ncol] = bf16_rne(__expf(acc1[r]));
                    }
                } else {                         // v, head h = wv-8 -> LDS
                    const int row0 = (wv - 8) * 32 + quad * 4;
                    #pragma unroll
                    for (int r = 0; r < 4; r++) {
                        vsh[(row0 + r) * 72 + ncol]      = bf16_rne(acc0[r]);
                        vsh[(row0 + 16 + r) * 72 + ncol] = bf16_rne(acc1[r]);
                    }
                }
            }
        } else {
            if (s + 1 < NSUB) { load_x(s + 1); store_x(xs_nxt); }   // overlaps gemm phase
        }
        __syncthreads();                         // B: ek/vsh ready; xs_nxt staged

        // context: cacc[d][e] += sum_n expk[d][n] * v[e][n]  (one 16x16 tile per wave)
        {
            const unsigned short* ap = &ek[(ch * 32 + cdt * 16 + l15) * 72 + quad * 8];
            const unsigned short* bp = &vsh[(ch * 32 + cet * 16 + l15) * 72 + quad * 8];
            #pragma unroll
            for (int kk = 0; kk < 2; kk++) {
                short8 a  = *(const short8*)(ap + kk * 32);
                short8 bb = *(const short8*)(bp + kk * 32);
                cacc = __builtin_amdgcn_mfma_f32_16x16x32_bf16(a, bb, cacc, 0, 0, 0);
            }
        }
        {   // S partial sums: 1024 threads = 128 rows x 8 threads x 8 elems
            const unsigned short* ep = &ek[(tid >> 3) * 72 + (tid & 7) * 8];
            short8 e0 = *(const short8*)ep;      // one ds_read_b128
            float ss = 0.f;
            #pragma unroll
            for (int j = 0; j < 8; j++) ss += bf2f((unsigned short)e0[j]);
            s_acc += ss;
        }
        { unsigned short* t = xs_cur; xs_cur = xs_nxt; xs_nxt = t; }
    }

    // write-out: plain stores, no atomics
    {
        float* cp = ctx_part + ((size_t)(b * TPB_ + tblk) << 12)
                  + ((ch * 32 + cdt * 16 + quad * 4) * 32 + cet * 16 + l15);
        #pragma unroll
        for (int r = 0; r < 4; r++) cp[r * 32] = cacc[r];
    }
    {
        float ss = s_acc;
        ss += __shfl_xor(ss, 1, 64);
        ss += __shfl_xor(ss, 2, 64);
        ss += __shfl_xor(ss, 4, 64);
        if ((tid & 7) == 0)
            S_part[(size_t)(b * TPB_ + tblk) * 128 + (tid >> 3)] = ss;
    }
}

// K2a: reduce 8 ctx partials + fold 1/S -> ctxn bf16 [b][hd][e] (flat [b][4096]).
// Grid 256 blocks (8/batch) x 256 thr: each thread 2 elems x 8 partials, full ILP.
__global__ __launch_bounds__(256) void k2a_reduce(const float* __restrict__ ctx_part,
                                                  const float* __restrict__ S_part,
                                                  unsigned short* __restrict__ ctxn) {
    __shared__ float Sinv[16];
    const int b     = blockIdx.x >> 3;
    const int chunk = blockIdx.x & 7;            // 512 elems (16 hd rows) per block
    const int tid   = threadIdx.x;
    if (tid < 16) {
        const int hd = chunk * 16 + tid;
        float s = 0.f;
        #pragma unroll
        for (int t = 0; t < TPB_; t++)
            s += S_part[(size_t)(b * TPB_ + t) * 128 + hd];
        Sinv[tid] = 1.0f / s;
    }
    __syncthreads();
    #pragma unroll
    for (int j = 0; j < 2; j++) {
        const int ei = chunk * 512 + j * 256 + tid;   // flat [hd][e]
        float v = 0.f;
        #pragma unroll
        for (int t = 0; t < TPB_; t++)
            v += ctx_part[((size_t)(b * TPB_ + t) << 12) + ei];
        ctxn[(size_t)b * 4096 + ei] = bf16_rne(v * Sinv[(ei >> 5) - chunk * 16]);
    }
}

// K2b: Wbig[b][o][hd] = sum_e wo[o][h*32+e] * ctxN[b][hd][e], written in FRAG-MAJOR
// tiled order: chunk c = (o>>4)*4 + (hd>>5); within chunk, lane' = ((hd>>3)&3)*16 + (o&15),
// short j = hd&7. k3 then stages linearly and reads lane-contiguous ds_read_b128.
// Grid 32 blocks x 512 thr; wave wv owns o-tile wv. All 12 loads hoisted (ILP).
__global__ __launch_bounds__(512) void k2b_fold(const unsigned short* __restrict__ ctxn,
                                                const unsigned short* __restrict__ wo,
                                                unsigned short* __restrict__ wbig) {
    const int b   = blockIdx.x;
    const int tid = threadIdx.x;
    const int lane = tid & 63, wv = tid >> 6, l15 = lane & 15, quad = lane >> 4;
    const float4v zero = {0.f, 0.f, 0.f, 0.f};

    short8 a4[4], b8[8];
    #pragma unroll
    for (int h = 0; h < 4; h++)
        a4[h] = *(const short8*)(wo + (wv * 16 + l15) * C_ + h * 32 + quad * 8);
    #pragma unroll
    for (int ht = 0; ht < 8; ht++)
        b8[ht] = *(const short8*)(ctxn + (size_t)b * 4096
                                  + ((ht >> 1) * 32 + (ht & 1) * 16 + l15) * 32 + quad * 8);

    unsigned short* wb = wbig + (size_t)b * (C_ * C_);
    #pragma unroll
    for (int ht = 0; ht < 8; ht++) {
        float4v c4 = __builtin_amdgcn_mfma_f32_16x16x32_bf16(a4[ht >> 1], b8[ht], zero, 0, 0, 0);
        // value (r): o = wv*16+quad*4+r, hd = ht*16+l15
        const int c     = wv * 4 + (ht >> 1);
        const int quadp = (ht & 1) * 2 + (l15 >> 3);
        #pragma unroll
        for (int r = 0; r < 4; r++)
            wb[((c * 64 + quadp * 16 + quad * 4 + r) << 3) + (l15 & 7)] = bf16_rne(c4[r]);
    }
}

// K3: single-phase y = Wbig[b] @ qsm + bout, LayerNorm over c.
// 512 thr / 128 n-cols per block. Wbig (32KB, frag-major) staged once into LDS via a
// linear copy; inner loop is lane-contiguous ds_read_b128 (conflict-free) + MFMA.
__global__ __launch_bounds__(512) void k3_out(const unsigned short* __restrict__ qsm,
                                              const unsigned short* __restrict__ wbig,
                                              const float* __restrict__ bout,
                                              const float* __restrict__ lnw,
                                              const float* __restrict__ lnb,
                                              float* __restrict__ out) {
    __shared__ __align__(16) unsigned short wls[16384];      // 32KB

    const int b   = blockIdx.y;
    const int n0  = blockIdx.x * 128;
    const int tid = threadIdx.x;

    const int lane = tid & 63, wv = tid >> 6, l15 = lane & 15, quad = lane >> 4;
    const int nl = wv * 16 + l15;
    const size_t n = (size_t)n0 + nl;

    const float4v zero = {0.f, 0.f, 0.f, 0.f};

    // stage Wbig[b] 32KB -> LDS (linear: thread t copies 16B chunks t, t+512, ...)
    short8 st[4];
    {
        const short8* src = (const short8*)(wbig + (size_t)b * (C_ * C_));
        #pragma unroll
        for (int i = 0; i < 4; i++) st[i] = src[i * 512 + tid];
    }
    // qsm B-frags for this n-column (independent loads, overlap the stage)
    short8 bq[4];
    #pragma unroll
    for (int kk = 0; kk < 4; kk++)
        bq[kk] = *(const short8*)(qsm + ((size_t)b * N_ + n) * C_ + kk * 32 + quad * 8);
    #pragma unroll
    for (int i = 0; i < 4; i++)
        *(short8*)&wls[(i * 512 + tid) * 8] = st[i];
    __syncthreads();

    float4v acc[8];
    #pragma unroll
    for (int ot = 0; ot < 8; ot++) {
        float4v a = zero;
        #pragma unroll
        for (int kk = 0; kk < 4; kk++) {
            short8 w = *(const short8*)&wls[(((ot * 4 + kk) * 64 + lane)) * 8];
            a = __builtin_amdgcn_mfma_f32_16x16x32_bf16(w, bq[kk], a, 0, 0, 0);
        }
        acc[ot] = a;
    }

    // bias + LayerNorm over the 128 channels of this column
    float sum = 0.f, sq = 0.f;
    #pragma unroll
    for (int ot = 0; ot < 8; ot++) {
        #pragma unroll
        for (int r = 0; r < 4; r++) {
            const int o = ot * 16 + quad * 4 + r;
            const float y = acc[ot][r] + bout[o];
            acc[ot][r] = y;
            sum += y; sq += y * y;
        }
    }
    sum += __shfl_xor(sum, 16, 64);
    sum += __shfl_xor(sum, 32, 64);
    sq  += __shfl_xor(sq, 16, 64);
    sq  += __shfl_xor(sq, 32, 64);
    const float mean = sum * (1.0f / 128.0f);
    const float var  = sq * (1.0f / 128.0f) - mean * mean;   // biased, matches jnp.var
    const float rstd = rsqrtf(var + 1e-5f);

    #pragma unroll
    for (int ot = 0; ot < 8; ot++) {
        #pragma unroll
        for (int r = 0; r < 4; r++) {
            const int o = ot * 16 + quad * 4 + r;
            out[((size_t)b * C_ + o) * N_ + n] = (acc[ot][r] - mean) * rstd * lnw[o] + lnb[o];
        }
    }
}

extern "C" void kernel_launch(void* const* d_in, const int* in_sizes, int n_in,
                              void* d_out, int out_size, void* d_ws, size_t ws_size,
                              hipStream_t stream) {
    const float* x    = (const float*)d_in[0];
    const float* Wqkv = (const float*)d_in[1];
    const float* Wout = (const float*)d_in[2];
    const float* bout = (const float*)d_in[3];
    const float* lnw  = (const float*)d_in[4];
    const float* lnb  = (const float*)d_in[5];
    float* out = (float*)d_out;

    char* ws = (char*)d_ws;
    unsigned short* wq   = (unsigned short*)(ws + OFF_WQ);
    unsigned short* wo   = (unsigned short*)(ws + OFF_WO);
    float* S_part        = (float*)(ws + OFF_SP);
    float* ctx_part      = (float*)(ws + OFF_CTXP);
    unsigned short* ctxn = (unsigned short*)(ws + OFF_CTXN);
    unsigned short* wbig = (unsigned short*)(ws + OFF_WBIG);
    unsigned short* qsm  = (unsigned short*)(ws + OFF_QSM);

    k0_prep<<<192, 256, 0, stream>>>(Wqkv, Wout, wq, wo);
    k1_qkv<<<dim3(TPB_, B_), 1024, 0, stream>>>(x, wq, qsm, ctx_part, S_part);
    k2a_reduce<<<B_ * 8, 256, 0, stream>>>(ctx_part, S_part, ctxn);
    k2b_fold<<<B_, 512, 0, stream>>>(ctxn, wo, wbig);
    k3_out<<<dim3(N_ / 128, B_), 512, 0, stream>>>(qsm, wbig, bout, lnw, lnb, out);
}

// Round 3
// 159.805 us; speedup vs baseline: 1.1341x; 1.0007x over previous
//
#include <hip/hip_runtime.h>
#include <stdint.h>

// LinearAttention fused: qkv GEMM + dual softmax + linear attention + Wout GEMM + LayerNorm2d
// Shapes: b=32, c=128, n=64*64=4096, heads=4, dim_head=32.
// All GEMMs via v_mfma_f32_16x16x32_bf16 (fp32 accum).
//
// R5: k1 rebuilt: 1024-thr blocks, 16 waves, wq frags persistent in VGPRs. 181us total.
// R6: algebraic fold y = (Wout @ blockdiag_h(ctxN)) @ qsm = Wbig[b] @ qsm. k3 single-phase.
// R7: Wbig written frag-major; k3 stages it in LDS (conflict-free ds_read_b128 inner
//     loop); k2 split into k2a (256 blk reduce) + k2b (fold). 159.9us. Top-5 now all
//     harness poison-fills (~40us each, fixed): k3 ~36us (inferred), k1 ~30us.
// R8: k3 at 36 vs ~20us floor: 512-thr block put VGPR in 65-128 class -> 16 waves/CU
//     = 2 blocks/CU; phase-structured kernel (load->barrier->MFMA->LN->store burst)
//     can't overlap phases with 2 blocks. Shrink to 256 thr / 64 n-cols: same VGPR
//     class but 4-wave blocks -> 4 co-resident blocks/CU (LDS 4x32KB=128KB), store
//     drain of one block overlaps loads/MFMA of three others. wbig reads double
//     (L2-hot, harmless). k1/k2 untouched for attribution.

constexpr int B_   = 32;
constexpr int C_   = 128;
constexpr int N_   = 4096;
constexpr int O3_  = 384;   // 3*128 qkv rows
constexpr int NSUB = 8;     // 64-wide n-subtiles per k1 block
constexpr int TPB_ = 8;     // k1 blocks per batch (4096 / 512)

using short8  = __attribute__((ext_vector_type(8))) short;
using short4v = __attribute__((ext_vector_type(4))) short;
using float4v = __attribute__((ext_vector_type(4))) float;

__device__ __forceinline__ unsigned short bf16_rne(float f) {
    union { float f; uint32_t u; } v; v.f = f;
    uint32_t u = v.u;
    u += 0x7FFFu + ((u >> 16) & 1u);   // round-to-nearest-even
    return (unsigned short)(u >> 16);
}
__device__ __forceinline__ float bf2f(unsigned short h) {
    union { uint32_t u; float f; } v; v.u = ((uint32_t)h) << 16; return v.f;
}

// workspace layout (bytes)
constexpr size_t OFF_WQ   = 0;          // Wqkv bf16: 384*128*2 = 98304
constexpr size_t OFF_WO   = 98304;      // Wout bf16: 128*128*2 = 32768 -> 131072
constexpr size_t OFF_SP   = 131072;     // S partials [b][8][128] f32: 131072 -> 262144
constexpr size_t OFF_CTXP = 262144;     // ctx partials [b][8][4096] f32: 4194304 -> 4456448
constexpr size_t OFF_CTXN = 4456448;    // ctxN bf16 [b][hd][e]: 262144 -> 4718592
constexpr size_t OFF_WBIG = 4718592;    // Wbig bf16 TILED [b][c=ot*4+kk][lane][8]: 1048576 -> 5767168
constexpr size_t OFF_QSM  = 5767168;    // q-softmax bf16 [b][n][h*32+d]: 33554432 -> 39321600
// total 39,321,600 bytes

__global__ __launch_bounds__(256) void k0_prep(const float* __restrict__ Wqkv,
                                               const float* __restrict__ Wout,
                                               unsigned short* __restrict__ wq,
                                               unsigned short* __restrict__ wo) {
    int t = blockIdx.x * 256 + threadIdx.x;      // grid = 192*256 = 49152
    if (t < O3_ * C_) wq[t] = bf16_rne(Wqkv[t]);
    if (t < C_ * C_)  wo[t] = bf16_rne(Wout[t]);
}

// K1: per (b, 512-wide n-tile): 16 waves. Waves 0-11: gemm wave w owns qkv row-pair w
// (rows w*32..w*32+31) with wq frags persistent in registers; covers all 64 n-cols.
// Waves 12-15: stage next x subtile (fp32->bf16, double-buffered). All 16 waves then
// run one context-MFMA tile each + S partial sums. Partials to global at end.
__global__ __launch_bounds__(1024) void k1_qkv(const float* __restrict__ x,
                                               const unsigned short* __restrict__ wq,
                                               unsigned short* __restrict__ qsm,
                                               float* __restrict__ ctx_part,
                                               float* __restrict__ S_part) {
    __shared__ __align__(16) unsigned short xs0[64 * 136];   // [n][c], stride 136 (dbuf A)
    __shared__ __align__(16) unsigned short xs1[64 * 136];   // dbuf B
    __shared__ __align__(16) unsigned short ek[128 * 72];    // [h*32+d][n], stride 72
    __shared__ __align__(16) unsigned short vsh[128 * 72];   // [h*32+e][n]

    const int b    = blockIdx.y;
    const int tblk = blockIdx.x;                 // 0..7
    const int tid  = threadIdx.x;

    const int lane = tid & 63;
    const int wv   = tid >> 6;                   // 0..15
    const int l15  = lane & 15;
    const int quad = lane >> 4;

    const float4v zero = {0.f, 0.f, 0.f, 0.f};

    // --- persistent wq fragments for gemm waves (loaded ONCE per block) ---
    short8 wfa[8];                               // [half(0: rows +0..15, 1: +16..31)*4 + kk]
    if (wv < 12) {
        const unsigned short* wqp = wq + (wv * 32 + l15) * C_ + quad * 8;
        #pragma unroll
        for (int kk = 0; kk < 4; kk++) {
            wfa[kk]     = *(const short8*)(wqp + kk * 32);
            wfa[4 + kk] = *(const short8*)(wqp + 16 * C_ + kk * 32);
        }
    }

    // --- staging lanes (waves 12-15): 256 threads, each 32 c-rows of one n ---
    const int sid = tid & 255;                   // for wv>=12: 0..255
    const int snl = sid & 63;                    // n within subtile
    const int scg = sid >> 6;                    // c group of 32
    const float* xbase = x + ((size_t)b * C_ + (size_t)scg * 32) * N_ + snl;
    float xv[32];
    auto load_x = [&](int s) {
        const float* xp = xbase + (tblk * NSUB + s) * 64;
        #pragma unroll
        for (int i = 0; i < 32; i++) xv[i] = xp[(size_t)i * N_];
    };
    auto store_x = [&](unsigned short* xs) {
        unsigned short* dst = &xs[snl * 136 + scg * 32];
        #pragma unroll
        for (int ii = 0; ii < 4; ii++) {
            short8 v8;
            #pragma unroll
            for (int j = 0; j < 8; j++) v8[j] = (short)bf16_rne(xv[ii * 8 + j]);
            *(short8*)(dst + ii * 8) = v8;
        }
    };

    if (wv >= 12) { load_x(0); store_x(xs0); }
    unsigned short* xs_cur = xs0;
    unsigned short* xs_nxt = xs1;

    float4v cacc = zero;                         // this wave's single ctx tile
    float s_acc  = 0.f;
    const int ch  = wv >> 2;                     // ctx tile coords (valid for all 16 wv)
    const int cdt = (wv >> 1) & 1;
    const int cet = wv & 1;

    for (int s = 0; s < NSUB; s++) {
        const int ns = (tblk * NSUB + s) * 64;
        __syncthreads();                         // A: xs_cur staged; ek/vsh free

        if (wv < 12) {
            #pragma unroll
            for (int ct = 0; ct < 4; ct++) {
                short8 bfx[4];
                #pragma unroll
                for (int kk = 0; kk < 4; kk++)
                    bfx[kk] = *(const short8*)&xs_cur[(ct * 16 + l15) * 136 + kk * 32 + quad * 8];
                float4v acc0 = zero, acc1 = zero;
                #pragma unroll
                for (int kk = 0; kk < 4; kk++) {
                    acc0 = __builtin_amdgcn_mfma_f32_16x16x32_bf16(wfa[kk],     bfx[kk], acc0, 0, 0, 0);
                    acc1 = __builtin_amdgcn_mfma_f32_16x16x32_bf16(wfa[4 + kk], bfx[kk], acc1, 0, 0, 0);
                }
                const int ncol = ct * 16 + l15;
                // C/D layout: col = l15, row = quad*4 + r (acc0: rows 0-15, acc1: 16-31)
                if (wv < 4) {                    // q, head h = wv: softmax over d per column
                    float e0[4], e1[4], z = 0.f;
                    #pragma unroll
                    for (int r = 0; r < 4; r++) {
                        e0[r] = __expf(acc0[r]); e1[r] = __expf(acc1[r]);
                        z += e0[r] + e1[r];
                    }
                    z += __shfl_xor(z, 16, 64);
                    z += __shfl_xor(z, 32, 64);
                    const float iz = 1.0f / z;
                    unsigned short* qp = qsm + ((size_t)b * N_ + ns + ncol) * C_ + wv * 32 + quad * 4;
                    short4v s0, s1;
                    #pragma unroll
                    for (int r = 0; r < 4; r++) {
                        s0[r] = (short)bf16_rne(e0[r] * iz);
                        s1[r] = (short)bf16_rne(e1[r] * iz);
                    }
                    *(short4v*)qp = s0;          // d = quad*4..+3
                    *(short4v*)(qp + 16) = s1;   // d = 16+quad*4..+3
                } else if (wv < 8) {             // k, head h = wv-4: exp -> LDS
                    const int row0 = (wv - 4) * 32 + quad * 4;
                    #pragma unroll
                    for (int r = 0; r < 4; r++) {
                        ek[(row0 + r) * 72 + ncol]      = bf16_rne(__expf(acc0[r]));
                        ek[(row0 + 16 + r) * 72 + ncol] = bf16_rne(__expf(acc1[r]));
                    }
                } else {                         // v, head h = wv-8 -> LDS
                    const int row0 = (wv - 8) * 32 + quad * 4;
                    #pragma unroll
                    for (int r = 0; r < 4; r++) {
                        vsh[(row0 + r) * 72 + ncol]      = bf16_rne(acc0[r]);
                        vsh[(row0 + 16 + r) * 72 + ncol] = bf16_rne(acc1[r]);
                    }
                }
            }
        } else {
            if (s + 1 < NSUB) { load_x(s + 1); store_x(xs_nxt); }   // overlaps gemm phase
        }
        __syncthreads();                         // B: ek/vsh ready; xs_nxt staged

        // context: cacc[d][e] += sum_n expk[d][n] * v[e][n]  (one 16x16 tile per wave)
        {
            const unsigned short* ap = &ek[(ch * 32 + cdt * 16 + l15) * 72 + quad * 8];
            const unsigned short* bp = &vsh[(ch * 32 + cet * 16 + l15) * 72 + quad * 8];
            #pragma unroll
            for (int kk = 0; kk < 2; kk++) {
                short8 a  = *(const short8*)(ap + kk * 32);
                short8 bb = *(const short8*)(bp + kk * 32);
                cacc = __builtin_amdgcn_mfma_f32_16x16x32_bf16(a, bb, cacc, 0, 0, 0);
            }
        }
        {   // S partial sums: 1024 threads = 128 rows x 8 threads x 8 elems
            const unsigned short* ep = &ek[(tid >> 3) * 72 + (tid & 7) * 8];
            short8 e0 = *(const short8*)ep;      // one ds_read_b128
            float ss = 0.f;
            #pragma unroll
            for (int j = 0; j < 8; j++) ss += bf2f((unsigned short)e0[j]);
            s_acc += ss;
        }
        { unsigned short* t = xs_cur; xs_cur = xs_nxt; xs_nxt = t; }
    }

    // write-out: plain stores, no atomics
    {
        float* cp = ctx_part + ((size_t)(b * TPB_ + tblk) << 12)
                  + ((ch * 32 + cdt * 16 + quad * 4) * 32 + cet * 16 + l15);
        #pragma unroll
        for (int r = 0; r < 4; r++) cp[r * 32] = cacc[r];
    }
    {
        float ss = s_acc;
        ss += __shfl_xor(ss, 1, 64);
        ss += __shfl_xor(ss, 2, 64);
        ss += __shfl_xor(ss, 4, 64);
        if ((tid & 7) == 0)
            S_part[(size_t)(b * TPB_ + tblk) * 128 + (tid >> 3)] = ss;
    }
}

// K2a: reduce 8 ctx partials + fold 1/S -> ctxn bf16 [b][hd][e] (flat [b][4096]).
// Grid 256 blocks (8/batch) x 256 thr: each thread 2 elems x 8 partials, full ILP.
__global__ __launch_bounds__(256) void k2a_reduce(const float* __restrict__ ctx_part,
                                                  const float* __restrict__ S_part,
                                                  unsigned short* __restrict__ ctxn) {
    __shared__ float Sinv[16];
    const int b     = blockIdx.x >> 3;
    const int chunk = blockIdx.x & 7;            // 512 elems (16 hd rows) per block
    const int tid   = threadIdx.x;
    if (tid < 16) {
        const int hd = chunk * 16 + tid;
        float s = 0.f;
        #pragma unroll
        for (int t = 0; t < TPB_; t++)
            s += S_part[(size_t)(b * TPB_ + t) * 128 + hd];
        Sinv[tid] = 1.0f / s;
    }
    __syncthreads();
    #pragma unroll
    for (int j = 0; j < 2; j++) {
        const int ei = chunk * 512 + j * 256 + tid;   // flat [hd][e]
        float v = 0.f;
        #pragma unroll
        for (int t = 0; t < TPB_; t++)
            v += ctx_part[((size_t)(b * TPB_ + t) << 12) + ei];
        ctxn[(size_t)b * 4096 + ei] = bf16_rne(v * Sinv[(ei >> 5) - chunk * 16]);
    }
}

// K2b: Wbig[b][o][hd] = sum_e wo[o][h*32+e] * ctxN[b][hd][e], written in FRAG-MAJOR
// tiled order: chunk c = (o>>4)*4 + (hd>>5); within chunk, lane' = ((hd>>3)&3)*16 + (o&15),
// short j = hd&7. k3 then stages linearly and reads lane-contiguous ds_read_b128.
// Grid 32 blocks x 512 thr; wave wv owns o-tile wv. All 12 loads hoisted (ILP).
__global__ __launch_bounds__(512) void k2b_fold(const unsigned short* __restrict__ ctxn,
                                                const unsigned short* __restrict__ wo,
                                                unsigned short* __restrict__ wbig) {
    const int b   = blockIdx.x;
    const int tid = threadIdx.x;
    const int lane = tid & 63, wv = tid >> 6, l15 = lane & 15, quad = lane >> 4;
    const float4v zero = {0.f, 0.f, 0.f, 0.f};

    short8 a4[4], b8[8];
    #pragma unroll
    for (int h = 0; h < 4; h++)
        a4[h] = *(const short8*)(wo + (wv * 16 + l15) * C_ + h * 32 + quad * 8);
    #pragma unroll
    for (int ht = 0; ht < 8; ht++)
        b8[ht] = *(const short8*)(ctxn + (size_t)b * 4096
                                  + ((ht >> 1) * 32 + (ht & 1) * 16 + l15) * 32 + quad * 8);

    unsigned short* wb = wbig + (size_t)b * (C_ * C_);
    #pragma unroll
    for (int ht = 0; ht < 8; ht++) {
        float4v c4 = __builtin_amdgcn_mfma_f32_16x16x32_bf16(a4[ht >> 1], b8[ht], zero, 0, 0, 0);
        // value (r): o = wv*16+quad*4+r, hd = ht*16+l15
        const int c     = wv * 4 + (ht >> 1);
        const int quadp = (ht & 1) * 2 + (l15 >> 3);
        #pragma unroll
        for (int r = 0; r < 4; r++)
            wb[((c * 64 + quadp * 16 + quad * 4 + r) << 3) + (l15 & 7)] = bf16_rne(c4[r]);
    }
}

// K3: single-phase y = Wbig[b] @ qsm + bout, LayerNorm over c.
// R8: 256 thr / 64 n-cols per block (4-wave blocks => 4 co-resident blocks/CU at
// 16 waves/CU; phases of independent blocks overlap). Wbig (32KB, frag-major) staged
// into LDS via linear copy; inner loop lane-contiguous ds_read_b128 (conflict-free).
__global__ __launch_bounds__(256) void k3_out(const unsigned short* __restrict__ qsm,
                                              const unsigned short* __restrict__ wbig,
                                              const float* __restrict__ bout,
                                              const float* __restrict__ lnw,
                                              const float* __restrict__ lnb,
                                              float* __restrict__ out) {
    __shared__ __align__(16) unsigned short wls[16384];      // 32KB

    const int b   = blockIdx.y;
    const int n0  = blockIdx.x * 64;
    const int tid = threadIdx.x;

    const int lane = tid & 63, wv = tid >> 6, l15 = lane & 15, quad = lane >> 4;
    const int nl = wv * 16 + l15;
    const size_t n = (size_t)n0 + nl;

    const float4v zero = {0.f, 0.f, 0.f, 0.f};

    // stage Wbig[b] 32KB -> LDS (linear: thread t copies 16B chunks t, t+256, ...)
    short8 st[8];
    {
        const short8* src = (const short8*)(wbig + (size_t)b * (C_ * C_));
        #pragma unroll
        for (int i = 0; i < 8; i++) st[i] = src[i * 256 + tid];
    }
    // qsm B-frags for this n-column (independent loads, overlap the stage)
    short8 bq[4];
    #pragma unroll
    for (int kk = 0; kk < 4; kk++)
        bq[kk] = *(const short8*)(qsm + ((size_t)b * N_ + n) * C_ + kk * 32 + quad * 8);
    #pragma unroll
    for (int i = 0; i < 8; i++)
        *(short8*)&wls[(i * 256 + tid) * 8] = st[i];
    __syncthreads();

    float4v acc[8];
    #pragma unroll
    for (int ot = 0; ot < 8; ot++) {
        float4v a = zero;
        #pragma unroll
        for (int kk = 0; kk < 4; kk++) {
            short8 w = *(const short8*)&wls[(((ot * 4 + kk) * 64 + lane)) * 8];
            a = __builtin_amdgcn_mfma_f32_16x16x32_bf16(w, bq[kk], a, 0, 0, 0);
        }
        acc[ot] = a;
    }

    // bias + LayerNorm over the 128 channels of this column
    float sum = 0.f, sq = 0.f;
    #pragma unroll
    for (int ot = 0; ot < 8; ot++) {
        #pragma unroll
        for (int r = 0; r < 4; r++) {
            const int o = ot * 16 + quad * 4 + r;
            const float y = acc[ot][r] + bout[o];
            acc[ot][r] = y;
            sum += y; sq += y * y;
        }
    }
    sum += __shfl_xor(sum, 16, 64);
    sum += __shfl_xor(sum, 32, 64);
    sq  += __shfl_xor(sq, 16, 64);
    sq  += __shfl_xor(sq, 32, 64);
    const float mean = sum * (1.0f / 128.0f);
    const float var  = sq * (1.0f / 128.0f) - mean * mean;   // biased, matches jnp.var
    const float rstd = rsqrtf(var + 1e-5f);

    #pragma unroll
    for (int ot = 0; ot < 8; ot++) {
        #pragma unroll
        for (int r = 0; r < 4; r++) {
            const int o = ot * 16 + quad * 4 + r;
            out[((size_t)b * C_ + o) * N_ + n] = (acc[ot][r] - mean) * rstd * lnw[o] + lnb[o];
        }
    }
}

extern "C" void kernel_launch(void* const* d_in, const int* in_sizes, int n_in,
                              void* d_out, int out_size, void* d_ws, size_t ws_size,
                              hipStream_t stream) {
    const float* x    = (const float*)d_in[0];
    const float* Wqkv = (const float*)d_in[1];
    const float* Wout = (const float*)d_in[2];
    const float* bout = (const float*)d_in[3];
    const float* lnw  = (const float*)d_in[4];
    const float* lnb  = (const float*)d_in[5];
    float* out = (float*)d_out;

    char* ws = (char*)d_ws;
    unsigned short* wq   = (unsigned short*)(ws + OFF_WQ);
    unsigned short* wo   = (unsigned short*)(ws + OFF_WO);
    float* S_part        = (float*)(ws + OFF_SP);
    float* ctx_part      = (float*)(ws + OFF_CTXP);
    unsigned short* ctxn = (unsigned short*)(ws + OFF_CTXN);
    unsigned short* wbig = (unsigned short*)(ws + OFF_WBIG);
    unsigned short* qsm  = (unsigned short*)(ws + OFF_QSM);

    k0_prep<<<192, 256, 0, stream>>>(Wqkv, Wout, wq, wo);
    k1_qkv<<<dim3(TPB_, B_), 1024, 0, stream>>>(x, wq, qsm, ctx_part, S_part);
    k2a_reduce<<<B_ * 8, 256, 0, stream>>>(ctx_part, S_part, ctxn);
    k2b_fold<<<B_, 512, 0, stream>>>(ctxn, wo, wbig);
    k3_out<<<dim3(N_ / 64, B_), 256, 0, stream>>>(qsm, wbig, bout, lnw, lnb, out);
}

// Round 4
// 158.401 us; speedup vs baseline: 1.1441x; 1.0089x over previous
//
#include <hip/hip_runtime.h>
#include <stdint.h>

// LinearAttention fused: qkv GEMM + dual softmax + linear attention + Wout GEMM + LayerNorm2d
// Shapes: b=32, c=128, n=64*64=4096, heads=4, dim_head=32.
// All GEMMs via v_mfma_f32_16x16x32_bf16 (fp32 accum).
//
// R5: k1 rebuilt: 1024-thr blocks, 16 waves, wq frags persistent in VGPRs. 181us total.
// R6: algebraic fold y = (Wout @ blockdiag_h(ctxN)) @ qsm = Wbig[b] @ qsm.
// R7: Wbig frag-major + k3 LDS-staged inner loop; k2 split. 159.9us.
// R8: k3 256-thr TLP attempt NEUTRAL: k3 VGPR was 64 all along -> already 4 blocks/CU.
//     Structure, not residency, is the stall: both k1 and k3 ~2.3x over HBM floors.
// R9: (a) k3 grid-stride persistent: 512 blocks (2/CU) x 2 tiles of 128 n-cols; wbig
//     staged ONCE per block (L2 stage traffic 64->16MB); bout/lnw/lnb in LDS (were ~96
//     scattered 4B loads/thread/tile); next tile's qsm frags prefetched before current
//     MFMA+stores. (b) k1 staging T14 split: phase s now {convert+ds_write subtile s+1
//     (loaded a phase ago), issue loads for s+2}; vmcnt round-trip leaves the barrier-B
//     critical path.

constexpr int B_   = 32;
constexpr int C_   = 128;
constexpr int N_   = 4096;
constexpr int O3_  = 384;   // 3*128 qkv rows
constexpr int NSUB = 8;     // 64-wide n-subtiles per k1 block
constexpr int TPB_ = 8;     // k1 blocks per batch (4096 / 512)

using short8  = __attribute__((ext_vector_type(8))) short;
using short4v = __attribute__((ext_vector_type(4))) short;
using float4v = __attribute__((ext_vector_type(4))) float;

__device__ __forceinline__ unsigned short bf16_rne(float f) {
    union { float f; uint32_t u; } v; v.f = f;
    uint32_t u = v.u;
    u += 0x7FFFu + ((u >> 16) & 1u);   // round-to-nearest-even
    return (unsigned short)(u >> 16);
}
__device__ __forceinline__ float bf2f(unsigned short h) {
    union { uint32_t u; float f; } v; v.u = ((uint32_t)h) << 16; return v.f;
}

// workspace layout (bytes)
constexpr size_t OFF_WQ   = 0;          // Wqkv bf16: 384*128*2 = 98304
constexpr size_t OFF_WO   = 98304;      // Wout bf16: 128*128*2 = 32768 -> 131072
constexpr size_t OFF_SP   = 131072;     // S partials [b][8][128] f32: 131072 -> 262144
constexpr size_t OFF_CTXP = 262144;     // ctx partials [b][8][4096] f32: 4194304 -> 4456448
constexpr size_t OFF_CTXN = 4456448;    // ctxN bf16 [b][hd][e]: 262144 -> 4718592
constexpr size_t OFF_WBIG = 4718592;    // Wbig bf16 TILED [b][c=ot*4+kk][lane][8]: 1048576 -> 5767168
constexpr size_t OFF_QSM  = 5767168;    // q-softmax bf16 [b][n][h*32+d]: 33554432 -> 39321600
// total 39,321,600 bytes

__global__ __launch_bounds__(256) void k0_prep(const float* __restrict__ Wqkv,
                                               const float* __restrict__ Wout,
                                               unsigned short* __restrict__ wq,
                                               unsigned short* __restrict__ wo) {
    int t = blockIdx.x * 256 + threadIdx.x;      // grid = 192*256 = 49152
    if (t < O3_ * C_) wq[t] = bf16_rne(Wqkv[t]);
    if (t < C_ * C_)  wo[t] = bf16_rne(Wout[t]);
}

// K1: per (b, 512-wide n-tile): 16 waves. Waves 0-11: gemm wave w owns qkv row-pair w
// (rows w*32..w*32+31) with wq frags persistent in registers; covers all 64 n-cols.
// Waves 12-15: stage x subtiles with a T14 issue-early/write-late pipeline:
//   phase s: convert+ds_write subtile s+1 (its loads issued in phase s-1), then
//   issue loads for subtile s+2. Only the convert+write gates barrier B.
__global__ __launch_bounds__(1024) void k1_qkv(const float* __restrict__ x,
                                               const unsigned short* __restrict__ wq,
                                               unsigned short* __restrict__ qsm,
                                               float* __restrict__ ctx_part,
                                               float* __restrict__ S_part) {
    __shared__ __align__(16) unsigned short xs0[64 * 136];   // [n][c], stride 136 (dbuf A)
    __shared__ __align__(16) unsigned short xs1[64 * 136];   // dbuf B
    __shared__ __align__(16) unsigned short ek[128 * 72];    // [h*32+d][n], stride 72
    __shared__ __align__(16) unsigned short vsh[128 * 72];   // [h*32+e][n]

    const int b    = blockIdx.y;
    const int tblk = blockIdx.x;                 // 0..7
    const int tid  = threadIdx.x;

    const int lane = tid & 63;
    const int wv   = tid >> 6;                   // 0..15
    const int l15  = lane & 15;
    const int quad = lane >> 4;

    const float4v zero = {0.f, 0.f, 0.f, 0.f};

    // --- persistent wq fragments for gemm waves (loaded ONCE per block) ---
    short8 wfa[8];                               // [half(0: rows +0..15, 1: +16..31)*4 + kk]
    if (wv < 12) {
        const unsigned short* wqp = wq + (wv * 32 + l15) * C_ + quad * 8;
        #pragma unroll
        for (int kk = 0; kk < 4; kk++) {
            wfa[kk]     = *(const short8*)(wqp + kk * 32);
            wfa[4 + kk] = *(const short8*)(wqp + 16 * C_ + kk * 32);
        }
    }

    // --- staging lanes (waves 12-15): 256 threads, each 32 c-rows of one n ---
    const int sid = tid & 255;                   // for wv>=12: 0..255
    const int snl = sid & 63;                    // n within subtile
    const int scg = sid >> 6;                    // c group of 32
    const float* xbase = x + ((size_t)b * C_ + (size_t)scg * 32) * N_ + snl;
    float xv[32];                                // raw loads (issued one phase early)
    short8 c16[4];                               // converted subtile, write-late
    auto load_x = [&](int s) {
        const float* xp = xbase + (tblk * NSUB + s) * 64;
        #pragma unroll
        for (int i = 0; i < 32; i++) xv[i] = xp[(size_t)i * N_];
    };
    auto conv_x = [&]() {
        #pragma unroll
        for (int ii = 0; ii < 4; ii++) {
            short8 v8;
            #pragma unroll
            for (int j = 0; j < 8; j++) v8[j] = (short)bf16_rne(xv[ii * 8 + j]);
            c16[ii] = v8;
        }
    };
    auto store_c = [&](unsigned short* xs) {
        unsigned short* dst = &xs[snl * 136 + scg * 32];
        #pragma unroll
        for (int ii = 0; ii < 4; ii++) *(short8*)(dst + ii * 8) = c16[ii];
    };

    if (wv >= 12) {
        load_x(0); conv_x(); store_c(xs0);       // subtile 0 staged
        load_x(1);                               // subtile 1 loads in flight into phase 0
    }
    unsigned short* xs_cur = xs0;
    unsigned short* xs_nxt = xs1;

    float4v cacc = zero;                         // this wave's single ctx tile
    float s_acc  = 0.f;
    const int ch  = wv >> 2;                     // ctx tile coords (valid for all 16 wv)
    const int cdt = (wv >> 1) & 1;
    const int cet = wv & 1;

    for (int s = 0; s < NSUB; s++) {
        const int ns = (tblk * NSUB + s) * 64;
        __syncthreads();                         // A: xs_cur staged; ek/vsh free

        if (wv < 12) {
            #pragma unroll
            for (int ct = 0; ct < 4; ct++) {
                short8 bfx[4];
                #pragma unroll
                for (int kk = 0; kk < 4; kk++)
                    bfx[kk] = *(const short8*)&xs_cur[(ct * 16 + l15) * 136 + kk * 32 + quad * 8];
                float4v acc0 = zero, acc1 = zero;
                #pragma unroll
                for (int kk = 0; kk < 4; kk++) {
                    acc0 = __builtin_amdgcn_mfma_f32_16x16x32_bf16(wfa[kk],     bfx[kk], acc0, 0, 0, 0);
                    acc1 = __builtin_amdgcn_mfma_f32_16x16x32_bf16(wfa[4 + kk], bfx[kk], acc1, 0, 0, 0);
                }
                const int ncol = ct * 16 + l15;
                // C/D layout: col = l15, row = quad*4 + r (acc0: rows 0-15, acc1: 16-31)
                if (wv < 4) {                    // q, head h = wv: softmax over d per column
                    float e0[4], e1[4], z = 0.f;
                    #pragma unroll
                    for (int r = 0; r < 4; r++) {
                        e0[r] = __expf(acc0[r]); e1[r] = __expf(acc1[r]);
                        z += e0[r] + e1[r];
                    }
                    z += __shfl_xor(z, 16, 64);
                    z += __shfl_xor(z, 32, 64);
                    const float iz = 1.0f / z;
                    unsigned short* qp = qsm + ((size_t)b * N_ + ns + ncol) * C_ + wv * 32 + quad * 4;
                    short4v s0, s1;
                    #pragma unroll
                    for (int r = 0; r < 4; r++) {
                        s0[r] = (short)bf16_rne(e0[r] * iz);
                        s1[r] = (short)bf16_rne(e1[r] * iz);
                    }
                    *(short4v*)qp = s0;          // d = quad*4..+3
                    *(short4v*)(qp + 16) = s1;   // d = 16+quad*4..+3
                } else if (wv < 8) {             // k, head h = wv-4: exp -> LDS
                    const int row0 = (wv - 4) * 32 + quad * 4;
                    #pragma unroll
                    for (int r = 0; r < 4; r++) {
                        ek[(row0 + r) * 72 + ncol]      = bf16_rne(__expf(acc0[r]));
                        ek[(row0 + 16 + r) * 72 + ncol] = bf16_rne(__expf(acc1[r]));
                    }
                } else {                         // v, head h = wv-8 -> LDS
                    const int row0 = (wv - 8) * 32 + quad * 4;
                    #pragma unroll
                    for (int r = 0; r < 4; r++) {
                        vsh[(row0 + r) * 72 + ncol]      = bf16_rne(acc0[r]);
                        vsh[(row0 + 16 + r) * 72 + ncol] = bf16_rne(acc1[r]);
                    }
                }
            }
        } else {
            if (s + 1 < NSUB) { conv_x(); store_c(xs_nxt); }  // loads from phase s-1
            if (s + 2 < NSUB) load_x(s + 2);                  // issue only; consumed next phase
        }
        __syncthreads();                         // B: ek/vsh ready; xs_nxt staged

        // context: cacc[d][e] += sum_n expk[d][n] * v[e][n]  (one 16x16 tile per wave)
        {
            const unsigned short* ap = &ek[(ch * 32 + cdt * 16 + l15) * 72 + quad * 8];
            const unsigned short* bp = &vsh[(ch * 32 + cet * 16 + l15) * 72 + quad * 8];
            #pragma unroll
            for (int kk = 0; kk < 2; kk++) {
                short8 a  = *(const short8*)(ap + kk * 32);
                short8 bb = *(const short8*)(bp + kk * 32);
                cacc = __builtin_amdgcn_mfma_f32_16x16x32_bf16(a, bb, cacc, 0, 0, 0);
            }
        }
        {   // S partial sums: 1024 threads = 128 rows x 8 threads x 8 elems
            const unsigned short* ep = &ek[(tid >> 3) * 72 + (tid & 7) * 8];
            short8 e0 = *(const short8*)ep;      // one ds_read_b128
            float ss = 0.f;
            #pragma unroll
            for (int j = 0; j < 8; j++) ss += bf2f((unsigned short)e0[j]);
            s_acc += ss;
        }
        { unsigned short* t = xs_cur; xs_cur = xs_nxt; xs_nxt = t; }
    }

    // write-out: plain stores, no atomics
    {
        float* cp = ctx_part + ((size_t)(b * TPB_ + tblk) << 12)
                  + ((ch * 32 + cdt * 16 + quad * 4) * 32 + cet * 16 + l15);
        #pragma unroll
        for (int r = 0; r < 4; r++) cp[r * 32] = cacc[r];
    }
    {
        float ss = s_acc;
        ss += __shfl_xor(ss, 1, 64);
        ss += __shfl_xor(ss, 2, 64);
        ss += __shfl_xor(ss, 4, 64);
        if ((tid & 7) == 0)
            S_part[(size_t)(b * TPB_ + tblk) * 128 + (tid >> 3)] = ss;
    }
}

// K2a: reduce 8 ctx partials + fold 1/S -> ctxn bf16 [b][hd][e] (flat [b][4096]).
// Grid 256 blocks (8/batch) x 256 thr: each thread 2 elems x 8 partials, full ILP.
__global__ __launch_bounds__(256) void k2a_reduce(const float* __restrict__ ctx_part,
                                                  const float* __restrict__ S_part,
                                                  unsigned short* __restrict__ ctxn) {
    __shared__ float Sinv[16];
    const int b     = blockIdx.x >> 3;
    const int chunk = blockIdx.x & 7;            // 512 elems (16 hd rows) per block
    const int tid   = threadIdx.x;
    if (tid < 16) {
        const int hd = chunk * 16 + tid;
        float s = 0.f;
        #pragma unroll
        for (int t = 0; t < TPB_; t++)
            s += S_part[(size_t)(b * TPB_ + t) * 128 + hd];
        Sinv[tid] = 1.0f / s;
    }
    __syncthreads();
    #pragma unroll
    for (int j = 0; j < 2; j++) {
        const int ei = chunk * 512 + j * 256 + tid;   // flat [hd][e]
        float v = 0.f;
        #pragma unroll
        for (int t = 0; t < TPB_; t++)
            v += ctx_part[((size_t)(b * TPB_ + t) << 12) + ei];
        ctxn[(size_t)b * 4096 + ei] = bf16_rne(v * Sinv[(ei >> 5) - chunk * 16]);
    }
}

// K2b: Wbig[b][o][hd] = sum_e wo[o][h*32+e] * ctxN[b][hd][e], written in FRAG-MAJOR
// tiled order: chunk c = (o>>4)*4 + (hd>>5); within chunk, lane' = ((hd>>3)&3)*16 + (o&15),
// short j = hd&7. k3 then stages linearly and reads lane-contiguous ds_read_b128.
// Grid 32 blocks x 512 thr; wave wv owns o-tile wv. All 12 loads hoisted (ILP).
__global__ __launch_bounds__(512) void k2b_fold(const unsigned short* __restrict__ ctxn,
                                                const unsigned short* __restrict__ wo,
                                                unsigned short* __restrict__ wbig) {
    const int b   = blockIdx.x;
    const int tid = threadIdx.x;
    const int lane = tid & 63, wv = tid >> 6, l15 = lane & 15, quad = lane >> 4;
    const float4v zero = {0.f, 0.f, 0.f, 0.f};

    short8 a4[4], b8[8];
    #pragma unroll
    for (int h = 0; h < 4; h++)
        a4[h] = *(const short8*)(wo + (wv * 16 + l15) * C_ + h * 32 + quad * 8);
    #pragma unroll
    for (int ht = 0; ht < 8; ht++)
        b8[ht] = *(const short8*)(ctxn + (size_t)b * 4096
                                  + ((ht >> 1) * 32 + (ht & 1) * 16 + l15) * 32 + quad * 8);

    unsigned short* wb = wbig + (size_t)b * (C_ * C_);
    #pragma unroll
    for (int ht = 0; ht < 8; ht++) {
        float4v c4 = __builtin_amdgcn_mfma_f32_16x16x32_bf16(a4[ht >> 1], b8[ht], zero, 0, 0, 0);
        // value (r): o = wv*16+quad*4+r, hd = ht*16+l15
        const int c     = wv * 4 + (ht >> 1);
        const int quadp = (ht & 1) * 2 + (l15 >> 3);
        #pragma unroll
        for (int r = 0; r < 4; r++)
            wb[((c * 64 + quadp * 16 + quad * 4 + r) << 3) + (l15 & 7)] = bf16_rne(c4[r]);
    }
}

// K3: grid-stride persistent y = Wbig[b] @ qsm + bout, LayerNorm over c.
// R9: 512 blocks (2/CU) x 512 thr; each block owns 256 n-cols = 2 tiles of 128.
// wbig (32KB frag-major) + bout/lnw/lnb staged into LDS ONCE per block; per tile the
// next tile's qsm frags are prefetched before the MFMA+store phase. One barrier total.
__global__ __launch_bounds__(512) void k3_out(const unsigned short* __restrict__ qsm,
                                              const unsigned short* __restrict__ wbig,
                                              const float* __restrict__ bout,
                                              const float* __restrict__ lnw,
                                              const float* __restrict__ lnb,
                                              float* __restrict__ out) {
    __shared__ __align__(16) unsigned short wls[16384];      // 32KB
    __shared__ float lnp[384];                               // bout | lnw | lnb

    const int b    = blockIdx.y;
    const int tseg = blockIdx.x;                 // 0..15: n-cols tseg*256 .. +255
    const int tid  = threadIdx.x;

    const int lane = tid & 63, wv = tid >> 6, l15 = lane & 15, quad = lane >> 4;
    const int nl = wv * 16 + l15;                // 0..127 within tile

    const float4v zero = {0.f, 0.f, 0.f, 0.f};
    const size_t n0base = (size_t)tseg * 256;

    // stage Wbig[b] 32KB -> LDS (linear: thread t copies 16B chunks t, t+512, ...)
    short8 st[4];
    {
        const short8* src = (const short8*)(wbig + (size_t)b * (C_ * C_));
        #pragma unroll
        for (int i = 0; i < 4; i++) st[i] = src[i * 512 + tid];
    }
    if (tid < 128) {
        lnp[tid]       = bout[tid];
        lnp[128 + tid] = lnw[tid];
        lnp[256 + tid] = lnb[tid];
    }
    // first tile's qsm B-frags (independent; overlap the stage)
    short8 bq[4], bqn[4];
    {
        const unsigned short* qp = qsm + ((size_t)b * N_ + n0base + nl) * C_ + quad * 8;
        #pragma unroll
        for (int kk = 0; kk < 4; kk++) bq[kk] = *(const short8*)(qp + kk * 32);
    }
    #pragma unroll
    for (int i = 0; i < 4; i++)
        *(short8*)&wls[(i * 512 + tid) * 8] = st[i];
    __syncthreads();

    #pragma unroll
    for (int t = 0; t < 2; t++) {
        const size_t n = n0base + t * 128 + nl;
        if (t == 0) {                            // prefetch next tile's frags
            const unsigned short* qp = qsm + ((size_t)b * N_ + n0base + 128 + nl) * C_ + quad * 8;
            #pragma unroll
            for (int kk = 0; kk < 4; kk++) bqn[kk] = *(const short8*)(qp + kk * 32);
        }

        float4v acc[8];
        #pragma unroll
        for (int ot = 0; ot < 8; ot++) {
            float4v a = zero;
            #pragma unroll
            for (int kk = 0; kk < 4; kk++) {
                short8 w = *(const short8*)&wls[((ot * 4 + kk) * 64 + lane) * 8];
                a = __builtin_amdgcn_mfma_f32_16x16x32_bf16(w, bq[kk], a, 0, 0, 0);
            }
            acc[ot] = a;
        }

        // bias + LayerNorm over the 128 channels of this column
        float sum = 0.f, sq = 0.f;
        #pragma unroll
        for (int ot = 0; ot < 8; ot++) {
            #pragma unroll
            for (int r = 0; r < 4; r++) {
                const int o = ot * 16 + quad * 4 + r;
                const float y = acc[ot][r] + lnp[o];
                acc[ot][r] = y;
                sum += y; sq += y * y;
            }
        }
        sum += __shfl_xor(sum, 16, 64);
        sum += __shfl_xor(sum, 32, 64);
        sq  += __shfl_xor(sq, 16, 64);
        sq  += __shfl_xor(sq, 32, 64);
        const float mean = sum * (1.0f / 128.0f);
        const float var  = sq * (1.0f / 128.0f) - mean * mean;   // biased, matches jnp.var
        const float rstd = rsqrtf(var + 1e-5f);

        #pragma unroll
        for (int ot = 0; ot < 8; ot++) {
            #pragma unroll
            for (int r = 0; r < 4; r++) {
                const int o = ot * 16 + quad * 4 + r;
                out[((size_t)b * C_ + o) * N_ + n] = (acc[ot][r] - mean) * rstd * lnp[128 + o] + lnp[256 + o];
            }
        }

        #pragma unroll
        for (int kk = 0; kk < 4; kk++) bq[kk] = bqn[kk];
    }
}

extern "C" void kernel_launch(void* const* d_in, const int* in_sizes, int n_in,
                              void* d_out, int out_size, void* d_ws, size_t ws_size,
                              hipStream_t stream) {
    const float* x    = (const float*)d_in[0];
    const float* Wqkv = (const float*)d_in[1];
    const float* Wout = (const float*)d_in[2];
    const float* bout = (const float*)d_in[3];
    const float* lnw  = (const float*)d_in[4];
    const float* lnb  = (const float*)d_in[5];
    float* out = (float*)d_out;

    char* ws = (char*)d_ws;
    unsigned short* wq   = (unsigned short*)(ws + OFF_WQ);
    unsigned short* wo   = (unsigned short*)(ws + OFF_WO);
    float* S_part        = (float*)(ws + OFF_SP);
    float* ctx_part      = (float*)(ws + OFF_CTXP);
    unsigned short* ctxn = (unsigned short*)(ws + OFF_CTXN);
    unsigned short* wbig = (unsigned short*)(ws + OFF_WBIG);
    unsigned short* qsm  = (unsigned short*)(ws + OFF_QSM);

    k0_prep<<<192, 256, 0, stream>>>(Wqkv, Wout, wq, wo);
    k1_qkv<<<dim3(TPB_, B_), 1024, 0, stream>>>(x, wq, qsm, ctx_part, S_part);
    k2a_reduce<<<B_ * 8, 256, 0, stream>>>(ctx_part, S_part, ctxn);
    k2b_fold<<<B_, 512, 0, stream>>>(ctxn, wo, wbig);
    k3_out<<<dim3(16, B_), 512, 0, stream>>>(qsm, wbig, bout, lnw, lnb, out);
}